// Round 1
// baseline (630.607 us; speedup 1.0000x reference)
//
#include <hip/hip_runtime.h>
#include <hip/hip_bf16.h>

#define NN 1024
#define FF 128

// ---------------------------------------------------------------------------
// Kernel A: extract filter diagonals d[f,m] = filters[f, m, m] into compact dw.
// 131072 elements; coalesced writes, strided (N+1)*4 = 4100 B reads.
// ---------------------------------------------------------------------------
__global__ __launch_bounds__(256) void diag_extract(const float* __restrict__ filters,
                                                    float* __restrict__ dw) {
    const int idx = blockIdx.x * 256 + threadIdx.x;  // idx = f*1024 + m
    const int f = idx >> 10;
    const int m = idx & 1023;
    dw[idx] = filters[(size_t)f * (NN * NN) + (size_t)m * (NN + 1)];
}

// ---------------------------------------------------------------------------
// Kernel B: zt[m, f] += d[f, m] * sum_n U[n, m] * x[n, f]
// Split-K over n (8 splits of 128). Tile: 32 m x 128 f. BK = 16.
// grid (32 m-tiles, 8 splits) = 256 blocks, 256 threads.
// Micro-tile per thread: 2 m x 8 f.
// ---------------------------------------------------------------------------
__global__ __launch_bounds__(256) void gemm1(const float* __restrict__ U,
                                             const float* __restrict__ x,
                                             const float* __restrict__ dw,
                                             float* __restrict__ zt) {
    __shared__ float As[16][32];    // [k][m] — U tile, staged directly (TN)
    __shared__ float Bs[16][128];   // [k][f] — x tile, staged directly

    const int tid = threadIdx.x;
    const int tm = tid & 15;        // 16 m-columns of threads
    const int tf = tid >> 4;        // 16 f-rows of threads
    const int m0 = blockIdx.x * 32;
    const int n0 = blockIdx.y * 128;

    float acc[2][8];
#pragma unroll
    for (int i = 0; i < 2; ++i)
#pragma unroll
        for (int j = 0; j < 8; ++j) acc[i][j] = 0.f;

    // staging index precompute
    const int ka = tid >> 4, ma = (tid & 15) * 2;   // As: float2 per thread
    const int kb = tid >> 5, fb = (tid & 31) * 4;   // Bs: 2x float4 per thread

    for (int kt = 0; kt < 8; ++kt) {
        const int nb = n0 + kt * 16;
        *(float2*)&As[ka][ma] = *(const float2*)&U[(size_t)(nb + ka) * NN + m0 + ma];
        *(float4*)&Bs[kb][fb]     = *(const float4*)&x[(size_t)(nb + kb) * FF + fb];
        *(float4*)&Bs[kb + 8][fb] = *(const float4*)&x[(size_t)(nb + kb + 8) * FF + fb];
        __syncthreads();
#pragma unroll
        for (int k = 0; k < 16; ++k) {
            const float2 a  = *(const float2*)&As[k][tm * 2];
            const float4 b0 = *(const float4*)&Bs[k][tf * 8];
            const float4 b1 = *(const float4*)&Bs[k][tf * 8 + 4];
            acc[0][0] += a.x * b0.x; acc[0][1] += a.x * b0.y;
            acc[0][2] += a.x * b0.z; acc[0][3] += a.x * b0.w;
            acc[0][4] += a.x * b1.x; acc[0][5] += a.x * b1.y;
            acc[0][6] += a.x * b1.z; acc[0][7] += a.x * b1.w;
            acc[1][0] += a.y * b0.x; acc[1][1] += a.y * b0.y;
            acc[1][2] += a.y * b0.z; acc[1][3] += a.y * b0.w;
            acc[1][4] += a.y * b1.x; acc[1][5] += a.y * b1.y;
            acc[1][6] += a.y * b1.z; acc[1][7] += a.y * b1.w;
        }
        __syncthreads();
    }

    // epilogue: scale by diagonal, atomic-accumulate split-K partials
#pragma unroll
    for (int i = 0; i < 2; ++i) {
        const int m = m0 + tm * 2 + i;
#pragma unroll
        for (int j = 0; j < 8; ++j) {
            const int f = tf * 8 + j;
            atomicAdd(&zt[(size_t)m * FF + f], acc[i][j] * dw[(size_t)f * NN + m]);
        }
    }
}

// ---------------------------------------------------------------------------
// Kernel C: out[f, n] += sum_m zt[m, f] * U[n, m]
// Split-K over m (8 splits of 128). Tile: 32 n x 128 f. BK = 16.
// U tile is transposed during LDS staging (pad 34 to break write conflicts).
// ---------------------------------------------------------------------------
__global__ __launch_bounds__(256) void gemm2(const float* __restrict__ U,
                                             const float* __restrict__ zt,
                                             float* __restrict__ out) {
    __shared__ float As[16][34];    // [k][n] — transposed U tile (pad +2)
    __shared__ float Bs[16][128];   // [k][f] — zt tile, staged directly

    const int tid = threadIdx.x;
    const int tn = tid & 15;
    const int tf = tid >> 4;
    const int n0 = blockIdx.x * 32;
    const int m0 = blockIdx.y * 128;

    float acc[2][8];
#pragma unroll
    for (int i = 0; i < 2; ++i)
#pragma unroll
        for (int j = 0; j < 8; ++j) acc[i][j] = 0.f;

    const int na = tid >> 3, kk = (tid & 7) * 2;    // As: float2 along m, transpose-write
    const int kb = tid >> 5, fb = (tid & 31) * 4;   // Bs: 2x float4 per thread

    for (int kt = 0; kt < 8; ++kt) {
        const int mb = m0 + kt * 16;
        const float2 v = *(const float2*)&U[(size_t)(n0 + na) * NN + mb + kk];
        As[kk][na]     = v.x;
        As[kk + 1][na] = v.y;
        *(float4*)&Bs[kb][fb]     = *(const float4*)&zt[(size_t)(mb + kb) * FF + fb];
        *(float4*)&Bs[kb + 8][fb] = *(const float4*)&zt[(size_t)(mb + kb + 8) * FF + fb];
        __syncthreads();
#pragma unroll
        for (int k = 0; k < 16; ++k) {
            const float2 a  = *(const float2*)&As[k][tn * 2];
            const float4 b0 = *(const float4*)&Bs[k][tf * 8];
            const float4 b1 = *(const float4*)&Bs[k][tf * 8 + 4];
            acc[0][0] += a.x * b0.x; acc[0][1] += a.x * b0.y;
            acc[0][2] += a.x * b0.z; acc[0][3] += a.x * b0.w;
            acc[0][4] += a.x * b1.x; acc[0][5] += a.x * b1.y;
            acc[0][6] += a.x * b1.z; acc[0][7] += a.x * b1.w;
            acc[1][0] += a.y * b0.x; acc[1][1] += a.y * b0.y;
            acc[1][2] += a.y * b0.z; acc[1][3] += a.y * b0.w;
            acc[1][4] += a.y * b1.x; acc[1][5] += a.y * b1.y;
            acc[1][6] += a.y * b1.z; acc[1][7] += a.y * b1.w;
        }
        __syncthreads();
    }

#pragma unroll
    for (int i = 0; i < 2; ++i) {
        const int n = n0 + tn * 2 + i;
#pragma unroll
        for (int j = 0; j < 8; ++j) {
            const int f = tf * 8 + j;
            atomicAdd(&out[(size_t)f * NN + n], acc[i][j]);
        }
    }
}

// ---------------------------------------------------------------------------
extern "C" void kernel_launch(void* const* d_in, const int* in_sizes, int n_in,
                              void* d_out, int out_size, void* d_ws, size_t ws_size,
                              hipStream_t stream) {
    const float* x       = (const float*)d_in[0];   // (1024, 128)
    const float* U       = (const float*)d_in[1];   // (1024, 1024)
    const float* filters = (const float*)d_in[2];   // (128, 1024, 1024), diagonal

    float* out = (float*)d_out;                     // (128, 1024)
    float* zt  = (float*)d_ws;                      // (1024, 128) intermediate
    float* dw  = zt + (size_t)NN * FF;              // (128, 1024) diagonals

    // d_out / d_ws are poisoned 0xAA before every call; we accumulate atomically.
    hipMemsetAsync(zt, 0, (size_t)NN * FF * sizeof(float), stream);
    hipMemsetAsync(out, 0, (size_t)out_size * sizeof(float), stream);

    diag_extract<<<dim3((NN * FF) / 256), 256, 0, stream>>>(filters, dw);
    gemm1<<<dim3(32, 8), 256, 0, stream>>>(U, x, dw, zt);
    gemm2<<<dim3(32, 8), 256, 0, stream>>>(U, zt, out);
}

// Round 2
// 597.634 us; speedup vs baseline: 1.0552x; 1.0552x over previous
//
#include <hip/hip_runtime.h>
#include <hip/hip_bf16.h>

#define NN 1024
#define FF 128
#define NSPLIT 8

// Workspace layout (floats):
//   zp[NSPLIT][FF][NN]  split-K partials of U^T x   (4 MiB)
//   zt[NN][FF]          diag-scaled reduced z        (512 KiB)
//   op[NSPLIT][FF][NN]  split-K partials of out      (4 MiB)
// No memsets / atomics needed: every buffer slice has exactly one writer.

// ---------------------------------------------------------------------------
// K1: zp[s][f][m] = sum_{n in split s} U[n,m] * x[n,f]
// Tile: 32 m x 128 f, BK=16, split-K over n (8 splits of 128). grid (32,8).
// ---------------------------------------------------------------------------
__global__ __launch_bounds__(256) void gemm1(const float* __restrict__ U,
                                             const float* __restrict__ x,
                                             float* __restrict__ zp) {
    __shared__ float As[16][32];    // [k][m] — U tile (TN, staged direct)
    __shared__ float Bs[16][128];   // [k][f] — x tile

    const int tid = threadIdx.x;
    const int tm = tid & 15;
    const int tf = tid >> 4;
    const int m0 = blockIdx.x * 32;
    const int s  = blockIdx.y;
    const int n0 = s * 128;

    float acc[2][8];
#pragma unroll
    for (int i = 0; i < 2; ++i)
#pragma unroll
        for (int j = 0; j < 8; ++j) acc[i][j] = 0.f;

    const int ka = tid >> 4, ma = (tid & 15) * 2;
    const int kb = tid >> 5, fb = (tid & 31) * 4;

    for (int kt = 0; kt < 8; ++kt) {
        const int nb = n0 + kt * 16;
        *(float2*)&As[ka][ma] = *(const float2*)&U[(size_t)(nb + ka) * NN + m0 + ma];
        *(float4*)&Bs[kb][fb]     = *(const float4*)&x[(size_t)(nb + kb) * FF + fb];
        *(float4*)&Bs[kb + 8][fb] = *(const float4*)&x[(size_t)(nb + kb + 8) * FF + fb];
        __syncthreads();
#pragma unroll
        for (int k = 0; k < 16; ++k) {
            const float2 a  = *(const float2*)&As[k][tm * 2];
            const float4 b0 = *(const float4*)&Bs[k][tf * 8];
            const float4 b1 = *(const float4*)&Bs[k][tf * 8 + 4];
            acc[0][0] += a.x * b0.x; acc[0][1] += a.x * b0.y;
            acc[0][2] += a.x * b0.z; acc[0][3] += a.x * b0.w;
            acc[0][4] += a.x * b1.x; acc[0][5] += a.x * b1.y;
            acc[0][6] += a.x * b1.z; acc[0][7] += a.x * b1.w;
            acc[1][0] += a.y * b0.x; acc[1][1] += a.y * b0.y;
            acc[1][2] += a.y * b0.z; acc[1][3] += a.y * b0.w;
            acc[1][4] += a.y * b1.x; acc[1][5] += a.y * b1.y;
            acc[1][6] += a.y * b1.z; acc[1][7] += a.y * b1.w;
        }
        __syncthreads();
    }

    // private-slice stores: zp[s][f][m], ~8 cache lines per wave-store
#pragma unroll
    for (int i = 0; i < 2; ++i) {
        const int m = m0 + tm * 2 + i;
#pragma unroll
        for (int j = 0; j < 8; ++j) {
            const int f = tf * 8 + j;
            zp[((size_t)s * FF + f) * NN + m] = acc[i][j];
        }
    }
}

// ---------------------------------------------------------------------------
// K2: zt[m][f] = filters[f][m][m] * sum_s zp[s][f][m]
// m-fast thread mapping: coalesced zp reads; scattered 4B zt writes (L2-hot).
// Folds the old diag_extract kernel in. 512 blocks x 256.
// ---------------------------------------------------------------------------
__global__ __launch_bounds__(256) void reduce_scale(const float* __restrict__ filters,
                                                    const float* __restrict__ zp,
                                                    float* __restrict__ zt) {
    const int idx = blockIdx.x * 256 + threadIdx.x;  // idx = f*1024 + m
    const int f = idx >> 10;
    const int m = idx & 1023;
    float s = 0.f;
#pragma unroll
    for (int sp = 0; sp < NSPLIT; ++sp)
        s += zp[((size_t)sp * FF + f) * NN + m];
    const float d = filters[(size_t)f * (NN * NN) + (size_t)m * (NN + 1)];
    zt[(size_t)m * FF + f] = s * d;
}

// ---------------------------------------------------------------------------
// K3: op[s][f][n] = sum_{m in split s} zt[m][f] * U[n,m]
// Tile: 32 n x 128 f, BK=16, split-K over m. grid (32,8).
// ---------------------------------------------------------------------------
__global__ __launch_bounds__(256) void gemm2(const float* __restrict__ U,
                                             const float* __restrict__ zt,
                                             float* __restrict__ op) {
    __shared__ float As[16][34];    // [k][n] — transposed U tile (pad +2)
    __shared__ float Bs[16][128];   // [k][f] — zt tile

    const int tid = threadIdx.x;
    const int tn = tid & 15;
    const int tf = tid >> 4;
    const int n0 = blockIdx.x * 32;
    const int s  = blockIdx.y;
    const int m0 = s * 128;

    float acc[2][8];
#pragma unroll
    for (int i = 0; i < 2; ++i)
#pragma unroll
        for (int j = 0; j < 8; ++j) acc[i][j] = 0.f;

    const int na = tid >> 3, kk = (tid & 7) * 2;
    const int kb = tid >> 5, fb = (tid & 31) * 4;

    for (int kt = 0; kt < 8; ++kt) {
        const int mb = m0 + kt * 16;
        const float2 v = *(const float2*)&U[(size_t)(n0 + na) * NN + mb + kk];
        As[kk][na]     = v.x;
        As[kk + 1][na] = v.y;
        *(float4*)&Bs[kb][fb]     = *(const float4*)&zt[(size_t)(mb + kb) * FF + fb];
        *(float4*)&Bs[kb + 8][fb] = *(const float4*)&zt[(size_t)(mb + kb + 8) * FF + fb];
        __syncthreads();
#pragma unroll
        for (int k = 0; k < 16; ++k) {
            const float2 a  = *(const float2*)&As[k][tn * 2];
            const float4 b0 = *(const float4*)&Bs[k][tf * 8];
            const float4 b1 = *(const float4*)&Bs[k][tf * 8 + 4];
            acc[0][0] += a.x * b0.x; acc[0][1] += a.x * b0.y;
            acc[0][2] += a.x * b0.z; acc[0][3] += a.x * b0.w;
            acc[0][4] += a.x * b1.x; acc[0][5] += a.x * b1.y;
            acc[0][6] += a.x * b1.z; acc[0][7] += a.x * b1.w;
            acc[1][0] += a.y * b0.x; acc[1][1] += a.y * b0.y;
            acc[1][2] += a.y * b0.z; acc[1][3] += a.y * b0.w;
            acc[1][4] += a.y * b1.x; acc[1][5] += a.y * b1.y;
            acc[1][6] += a.y * b1.z; acc[1][7] += a.y * b1.w;
        }
        __syncthreads();
    }

#pragma unroll
    for (int i = 0; i < 2; ++i) {
        const int n = n0 + tn * 2 + i;
#pragma unroll
        for (int j = 0; j < 8; ++j) {
            const int f = tf * 8 + j;
            op[((size_t)s * FF + f) * NN + n] = acc[i][j];
        }
    }
}

// ---------------------------------------------------------------------------
// K4: out[f][n] = sum_s op[s][f][n]   — fully coalesced reads & writes.
// ---------------------------------------------------------------------------
__global__ __launch_bounds__(256) void reduce_out(const float* __restrict__ op,
                                                  float* __restrict__ out) {
    const int idx = blockIdx.x * 256 + threadIdx.x;  // idx = f*1024 + n
    float s = 0.f;
#pragma unroll
    for (int sp = 0; sp < NSPLIT; ++sp)
        s += op[(size_t)sp * FF * NN + idx];
    out[idx] = s;
}

// ---------------------------------------------------------------------------
extern "C" void kernel_launch(void* const* d_in, const int* in_sizes, int n_in,
                              void* d_out, int out_size, void* d_ws, size_t ws_size,
                              hipStream_t stream) {
    const float* x       = (const float*)d_in[0];   // (1024, 128)
    const float* U       = (const float*)d_in[1];   // (1024, 1024)
    const float* filters = (const float*)d_in[2];   // (128, 1024, 1024), diagonal

    float* out = (float*)d_out;                     // (128, 1024)
    float* zp  = (float*)d_ws;                      // [8][128][1024]
    float* zt  = zp + (size_t)NSPLIT * FF * NN;     // [1024][128]
    float* op  = zt + (size_t)NN * FF;              // [8][128][1024]

    gemm1<<<dim3(32, 8), 256, 0, stream>>>(U, x, zp);
    reduce_scale<<<dim3((NN * FF) / 256), 256, 0, stream>>>(filters, zp, zt);
    gemm2<<<dim3(32, 8), 256, 0, stream>>>(U, zt, op);
    reduce_out<<<dim3((NN * FF) / 256), 256, 0, stream>>>(op, out);
}